// Round 4
// baseline (72.414 us; speedup 1.0000x reference)
//
#include <hip/hip_runtime.h>
#include <hip/hip_bf16.h>

// ---------------------------------------------------------------------------
// scores[y,x] = sum_h W2[h] * ( sum_{m,n} leaky( py[y,h,m,:].px[x,h,n,:] /8 ) ) / (nItem[x]*64)
// SINGLE fused kernel, 384 blocks (all co-resident):
//   blocks 0..71  : gallery+px prep (64 x-rows; Wp frag image in 16KB LDS quarters)
//   blocks 72..167: py prep (one yi each)
//   ALL blocks    : spin on device-scope done-flags, then pairwise att
//                   (wave = 1 yi x 6 xi, A-frags register-resident).
// Flag protocol: producers release-store MAGIC; consumers poll relaxed agent
// loads + one threadfence; last finisher resets flags -> stateless across calls.
// Fragment map (A and B of mfma_f32_16x16x32_bf16, same map):
//   lane l holds (rc=l&15, k=8*(l>>4)+i), i=0..7.  C/D: col=l&15, row=(l>>4)*4+j.
// py image: [y][h][mt(4)][kc(2)][lane(64)][i(8)]
// px image: [x][h][nt(3)][kc(2)][lane(64)][i(8)]
// ---------------------------------------------------------------------------

typedef short bf16x8 __attribute__((ext_vector_type(8)));
typedef float f32x4 __attribute__((ext_vector_type(4)));

#define NPROD 168
#define NBLK  384
#define MAGIC 0x13572468u

__device__ __forceinline__ unsigned short f2bf(float v) {
  __hip_bfloat16 b = __float2bfloat16(v);
  return *reinterpret_cast<unsigned short*>(&b);
}

__device__ __forceinline__ bf16x8 load8_cvt(const float* __restrict__ p) {
  f32x4 v0 = *reinterpret_cast<const f32x4*>(p);
  f32x4 v1 = *reinterpret_cast<const f32x4*>(p + 4);
  bf16x8 r;
  r[0] = (short)f2bf(v0[0]); r[1] = (short)f2bf(v0[1]);
  r[2] = (short)f2bf(v0[2]); r[3] = (short)f2bf(v0[3]);
  r[4] = (short)f2bf(v1[0]); r[5] = (short)f2bf(v1[1]);
  r[6] = (short)f2bf(v1[2]); r[7] = (short)f2bf(v1[3]);
  return r;
}

__global__ __launch_bounds__(256, 2) void k_fused(const float* __restrict__ x,
                                                  const float* __restrict__ y,
                                                  const float* __restrict__ Wp,
                                                  const float* __restrict__ W1,
                                                  const float* __restrict__ nItem,
                                                  const float* __restrict__ W2,
                                                  unsigned short* __restrict__ pyf,
                                                  unsigned short* __restrict__ pxf,
                                                  unsigned int* flags,
                                                  float* __restrict__ out) {
  __shared__ unsigned short w1f[8192];      // frag f=kc*8+nt: [f][lane][8]  16KB
  __shared__ unsigned short wpf[8192];      // quarter: g=kk*4+nt: [g][lane][8] 16KB
  __shared__ unsigned short gal[4][1152];   // per-wave 16 x 72 (padded)      9KB
  int t = threadIdx.x;
  int lane = t & 63, w = t >> 6;
  int b = blockIdx.x;

  float w2h0 = W2[0], w2h1 = W2[1];         // hoisted before spin

  // ======================= prep phase (producers only) =====================
  if (b < NPROD) {
    // build W1 frag image (both producer types need it)
#pragma unroll
    for (int it = 0; it < 32; ++it) {
      int idx = it * 256 + t;                // over 64*128
      int k = idx >> 7, d = idx & 127;
      int l = (d & 15) + 16 * ((k >> 3) & 3);
      int f = (k >> 5) * 8 + (d >> 4);
      w1f[f * 512 + l * 8 + (k & 7)] = f2bf(W1[idx]);
    }
    if (b >= 72) {
      // ------------------------- py: yi = b - 72 ---------------------------
      __syncthreads();
      int yi = b - 72;
      const bf16x8* WF = reinterpret_cast<const bf16x8*>(w1f);
      int row0 = yi * 64 + w * 16 + (lane & 15);
      const float* yb = y + (size_t)row0 * 64 + 8 * (lane >> 4);
      bf16x8 a0 = load8_cvt(yb);
      bf16x8 a1 = load8_cvt(yb + 32);
      f32x4 acc[8];
#pragma unroll
      for (int nt = 0; nt < 8; ++nt) acc[nt] = (f32x4){0.f, 0.f, 0.f, 0.f};
#pragma unroll
      for (int nt = 0; nt < 8; ++nt) {
        acc[nt] = __builtin_amdgcn_mfma_f32_16x16x32_bf16(a0, WF[nt * 64 + lane], acc[nt], 0, 0, 0);
        acc[nt] = __builtin_amdgcn_mfma_f32_16x16x32_bf16(a1, WF[(8 + nt) * 64 + lane], acc[nt], 0, 0, 0);
      }
      int r_hi = (lane >> 4) * 4;
#pragma unroll
      for (int nt = 0; nt < 8; ++nt) {
        int d = nt * 16 + (lane & 15);
        int h = d >> 6, dd = d & 63;
        int kc = dd >> 5, q = (dd >> 3) & 3, i = dd & 7;
#pragma unroll
        for (int j = 0; j < 4; ++j) {
          int m = w * 16 + r_hi + j;
          int mt = m >> 4, rr = m & 15;
          size_t idx = ((size_t)((yi * 2 + h) * 8 + mt * 2 + kc)) * 512 + (rr + (q << 4)) * 8 + i;
          pyf[idx] = f2bf(acc[nt][j]);
        }
      }
    } else {
      // -------------------- gallery+px: 64 rows of x -----------------------
      int rowbase = b * 64;
      const bf16x8* WPF = reinterpret_cast<const bf16x8*>(wpf);
      const bf16x8* WF = reinterpret_cast<const bf16x8*>(w1f);
      int rloc = rowbase + w * 16 + (lane & 15);
      const float* xb = x + (size_t)rloc * 512 + 8 * (lane >> 4);
      f32x4 acc1[4];
#pragma unroll
      for (int nt = 0; nt < 4; ++nt) acc1[nt] = (f32x4){0.f, 0.f, 0.f, 0.f};
#pragma unroll
      for (int q = 0; q < 4; ++q) {          // K quarters of 128
        if (q) __syncthreads();              // protect previous quarter's reads
#pragma unroll
        for (int it = 0; it < 32; ++it) {
          int idx = it * 256 + t;            // over 128*64
          int kq = idx >> 6, c = idx & 63;
          int l = (c & 15) + 16 * ((kq >> 3) & 3);
          int g = ((kq >> 5) & 3) * 4 + (c >> 4);
          wpf[g * 512 + l * 8 + (kq & 7)] = f2bf(Wp[(q * 128 + kq) * 64 + c]);
        }
        __syncthreads();
#pragma unroll
        for (int kk = 0; kk < 4; ++kk) {
          int kc = q * 4 + kk;
          bf16x8 a = load8_cvt(xb + 32 * kc);
#pragma unroll
          for (int nt = 0; nt < 4; ++nt)
            acc1[nt] = __builtin_amdgcn_mfma_f32_16x16x32_bf16(a, WPF[(kk * 4 + nt) * 64 + lane], acc1[nt], 0, 0, 0);
        }
      }
      // gelu -> own-wave gal tile (same-wave LDS RAW, no barrier needed)
#pragma unroll
      for (int nt = 0; nt < 4; ++nt)
#pragma unroll
        for (int j = 0; j < 4; ++j) {
          float s = acc1[nt][j];
          float ge = 0.5f * s * (1.0f + erff(s * 0.70710678118654752f));
          int rl = (lane >> 4) * 4 + j;
          int c = nt * 16 + (lane & 15);
          gal[w][rl * 72 + c] = f2bf(ge);
        }
      const unsigned short* gp = &gal[w][(lane & 15) * 72 + 8 * (lane >> 4)];
      bf16x8 g0 = *reinterpret_cast<const bf16x8*>(gp);
      bf16x8 g1 = *reinterpret_cast<const bf16x8*>(gp + 32);
      f32x4 acc2[8];
#pragma unroll
      for (int nt = 0; nt < 8; ++nt) acc2[nt] = (f32x4){0.f, 0.f, 0.f, 0.f};
#pragma unroll
      for (int nt = 0; nt < 8; ++nt) {
        acc2[nt] = __builtin_amdgcn_mfma_f32_16x16x32_bf16(g0, WF[nt * 64 + lane], acc2[nt], 0, 0, 0);
        acc2[nt] = __builtin_amdgcn_mfma_f32_16x16x32_bf16(g1, WF[(8 + nt) * 64 + lane], acc2[nt], 0, 0, 0);
      }
      int r_hi = (lane >> 4) * 4;
#pragma unroll
      for (int nt = 0; nt < 8; ++nt) {
        int d = nt * 16 + (lane & 15);
        int h = d >> 6, dd = d & 63;
        int kc = dd >> 5, q2 = (dd >> 3) & 3, i = dd & 7;
#pragma unroll
        for (int j = 0; j < 4; ++j) {
          int row = rowbase + w * 16 + r_hi + j;
          int xi = row / 48, n = row % 48;
          int nt3 = n >> 4, rr = n & 15;
          size_t idx = ((size_t)((xi * 2 + h) * 6 + nt3 * 2 + kc)) * 512 + (rr + (q2 << 4)) * 8 + i;
          pxf[idx] = f2bf(acc2[nt][j]);
        }
      }
    }
  }

  // ============================ release + spin =============================
  __syncthreads();   // per-wave vmcnt(0) drain before barrier -> all stores done
  if (b < NPROD && t == 0)
    __hip_atomic_store(&flags[b], MAGIC, __ATOMIC_RELEASE, __HIP_MEMORY_SCOPE_AGENT);
  for (;;) {
    unsigned v = (t < NPROD)
        ? __hip_atomic_load(&flags[t], __ATOMIC_RELAXED, __HIP_MEMORY_SCOPE_AGENT)
        : MAGIC;
    if (__syncthreads_count((int)(v == MAGIC)) == 256) break;
  }
  __threadfence();   // acquire: invalidate L1/L2 before reading pyf/pxf

  // ================================ att ====================================
  {
    int yb2 = b >> 4, xq = b & 15;
    int yi = yb2 * 4 + w;
    int xi0 = xq * 6;
    const bf16x8* PA = reinterpret_cast<const bf16x8*>(pyf);
    const bf16x8* PB = reinterpret_cast<const bf16x8*>(pxf);

    f32x4 zero4 = {0.f, 0.f, 0.f, 0.f};
    asm volatile("" : "+v"(zero4));

    bf16x8 a[16];
    size_t abase = (size_t)(yi * 2) * 512 + lane;
#pragma unroll
    for (int f = 0; f < 8; ++f) {
      a[f]     = PA[abase + f * 64];
      a[8 + f] = PA[abase + 512 + f * 64];
    }
    float res[6];
#pragma unroll
    for (int g = 0; g < 6; ++g) {
      int xi = xi0 + g;
      f32x4 szw = {0.f, 0.f, 0.f, 0.f};
      f32x4 srw = {0.f, 0.f, 0.f, 0.f};
#pragma unroll
      for (int h = 0; h < 2; ++h) {
        size_t bbase = (size_t)((xi * 2 + h) * 6) * 64 + lane;
        bf16x8 bb[6];
#pragma unroll
        for (int f = 0; f < 6; ++f) bb[f] = PB[bbase + f * 64];
        float c3 = 0.3f * (h ? w2h1 : w2h0);
        float c7 = 0.7f * (h ? w2h1 : w2h0);
#pragma unroll
        for (int nt = 0; nt < 3; ++nt)
#pragma unroll
          for (int mt = 0; mt < 4; ++mt) {
            f32x4 acc = __builtin_amdgcn_mfma_f32_16x16x32_bf16(a[h * 8 + mt * 2], bb[nt * 2], zero4, 0, 0, 0);
            acc = __builtin_amdgcn_mfma_f32_16x16x32_bf16(a[h * 8 + mt * 2 + 1], bb[nt * 2 + 1], acc, 0, 0, 0);
            f32x4 mx = {fmaxf(acc[0], 0.f), fmaxf(acc[1], 0.f), fmaxf(acc[2], 0.f), fmaxf(acc[3], 0.f)};
            szw += acc * c3;
            srw += mx * c7;
          }
      }
      f32x4 t4 = szw + srw;
      float tot = (t4[0] + t4[1]) + (t4[2] + t4[3]);
#pragma unroll
      for (int off = 32; off >= 1; off >>= 1) tot += __shfl_xor(tot, off, 64);
      res[g] = tot;
    }
    if (lane == 0) {
#pragma unroll
      for (int g = 0; g < 6; ++g)
        out[yi * 96 + xi0 + g] = res[g] / (512.0f * nItem[xi0 + g]);
    }
  }

  // ===================== finish counter + self-reset =======================
  __syncthreads();   // drain out-stores of all waves
  if (t == 0) {
    unsigned n = __hip_atomic_fetch_add(&flags[NPROD], 1u, __ATOMIC_ACQ_REL, __HIP_MEMORY_SCOPE_AGENT);
    if (n == NBLK - 1) {
      for (int i = 0; i <= NPROD; ++i)
        __hip_atomic_store(&flags[i], 0u, __ATOMIC_RELAXED, __HIP_MEMORY_SCOPE_AGENT);
    }
  }
}

// ---------------------------------------------------------------------------
extern "C" void kernel_launch(void* const* d_in, const int* in_sizes, int n_in,
                              void* d_out, int out_size, void* d_ws, size_t ws_size,
                              hipStream_t stream) {
  const float* x     = (const float*)d_in[0]; // [96,48,512]
  const float* y     = (const float*)d_in[1]; // [96,64,64]
  const float* nItem = (const float*)d_in[2]; // [96]
  const float* Wp    = (const float*)d_in[3]; // [512,64]
  const float* W1    = (const float*)d_in[4]; // [64,128]
  const float* W2    = (const float*)d_in[5]; // [2,1]
  float* out = (float*)d_out;                 // [96,96,1]

  unsigned short* pyf = (unsigned short*)d_ws;         // 786432 u16 (1.5MB)
  unsigned short* pxf = pyf + 786432;                  // 589824 u16 (1.125MB)
  unsigned int* flags = (unsigned int*)(pxf + 589824); // 169 u32

  hipLaunchKernelGGL(k_fused, dim3(NBLK), dim3(256), 0, stream,
                     x, y, Wp, W1, nItem, W2, pyf, pxf, flags, out);
}

// Round 5
// 56.952 us; speedup vs baseline: 1.2715x; 1.2715x over previous
//
#include <hip/hip_runtime.h>
#include <hip/hip_bf16.h>

// ---------------------------------------------------------------------------
// scores[y,x] = sum_h W2[h] * ( sum_{m,n} leaky( py[y,h,m,:].px[x,h,n,:] /8 ) ) / (nItem[x]*64)
// SINGLE fused kernel, 384 blocks (all co-resident):
//   blocks 0..71  : gallery+px prep (64 x-rows; Wp frag image in 16KB LDS quarters)
//   blocks 72..167: py prep (one yi each)
//   ALL blocks    : wait on a single done-counter, then pairwise att
//                   (wave = 1 yi x 6 xi, A-frags register-resident).
// Sync protocol (cheap version — round-4's was a coherence-storm):
//   producer: __syncthreads (drains vmcnt -> stores in local L2), then thread0
//             fetch_add(counter, RELEASE, agent) -> emits buffer_wbl2 first,
//             so all block stores reach the coherence point before the count.
//   consumer: thread0 polls counter==168 with s_sleep backoff; others wait at
//             s_barrier. NO acquire/invalidate needed: dispatch-start acquire
//             cleaned L2s, and no block reads pyf/pxf before its spin exits,
//             so consumer L2 lines of pyf/pxf can only be post-writeback.
//   counter zeroed each replay by an 8-byte hipMemsetAsync node before launch.
// Fragment map (A and B of mfma_f32_16x16x32_bf16, same map):
//   lane l holds (rc=l&15, k=8*(l>>4)+i), i=0..7.  C/D: col=l&15, row=(l>>4)*4+j.
// py image: [y][h][mt(4)][kc(2)][lane(64)][i(8)]
// px image: [x][h][nt(3)][kc(2)][lane(64)][i(8)]
// ---------------------------------------------------------------------------

typedef short bf16x8 __attribute__((ext_vector_type(8)));
typedef float f32x4 __attribute__((ext_vector_type(4)));

#define NPROD 168u
#define NBLK  384

__device__ __forceinline__ unsigned short f2bf(float v) {
  __hip_bfloat16 b = __float2bfloat16(v);
  return *reinterpret_cast<unsigned short*>(&b);
}

__device__ __forceinline__ bf16x8 load8_cvt(const float* __restrict__ p) {
  f32x4 v0 = *reinterpret_cast<const f32x4*>(p);
  f32x4 v1 = *reinterpret_cast<const f32x4*>(p + 4);
  bf16x8 r;
  r[0] = (short)f2bf(v0[0]); r[1] = (short)f2bf(v0[1]);
  r[2] = (short)f2bf(v0[2]); r[3] = (short)f2bf(v0[3]);
  r[4] = (short)f2bf(v1[0]); r[5] = (short)f2bf(v1[1]);
  r[6] = (short)f2bf(v1[2]); r[7] = (short)f2bf(v1[3]);
  return r;
}

__global__ __launch_bounds__(256, 2) void k_fused(const float* __restrict__ x,
                                                  const float* __restrict__ y,
                                                  const float* __restrict__ Wp,
                                                  const float* __restrict__ W1,
                                                  const float* __restrict__ nItem,
                                                  const float* __restrict__ W2,
                                                  unsigned short* __restrict__ pyf,
                                                  unsigned short* __restrict__ pxf,
                                                  unsigned int* flags,
                                                  float* __restrict__ out) {
  __shared__ unsigned short w1f[8192];      // frag f=kc*8+nt: [f][lane][8]  16KB
  __shared__ unsigned short wpf[8192];      // quarter: g=kk*4+nt: [g][lane][8] 16KB
  __shared__ unsigned short gal[4][1152];   // per-wave 16 x 72 (padded)      9KB
  int t = threadIdx.x;
  int lane = t & 63, w = t >> 6;
  int b = blockIdx.x;

  float w2h0 = W2[0], w2h1 = W2[1];         // hoisted before wait

  // ======================= prep phase (producers only) =====================
  if (b < (int)NPROD) {
    // build W1 frag image (both producer types need it)
#pragma unroll
    for (int it = 0; it < 32; ++it) {
      int idx = it * 256 + t;                // over 64*128
      int k = idx >> 7, d = idx & 127;
      int l = (d & 15) + 16 * ((k >> 3) & 3);
      int f = (k >> 5) * 8 + (d >> 4);
      w1f[f * 512 + l * 8 + (k & 7)] = f2bf(W1[idx]);
    }
    if (b >= 72) {
      // ------------------------- py: yi = b - 72 ---------------------------
      __syncthreads();
      int yi = b - 72;
      const bf16x8* WF = reinterpret_cast<const bf16x8*>(w1f);
      int row0 = yi * 64 + w * 16 + (lane & 15);
      const float* yb = y + (size_t)row0 * 64 + 8 * (lane >> 4);
      bf16x8 a0 = load8_cvt(yb);
      bf16x8 a1 = load8_cvt(yb + 32);
      f32x4 acc[8];
#pragma unroll
      for (int nt = 0; nt < 8; ++nt) acc[nt] = (f32x4){0.f, 0.f, 0.f, 0.f};
#pragma unroll
      for (int nt = 0; nt < 8; ++nt) {
        acc[nt] = __builtin_amdgcn_mfma_f32_16x16x32_bf16(a0, WF[nt * 64 + lane], acc[nt], 0, 0, 0);
        acc[nt] = __builtin_amdgcn_mfma_f32_16x16x32_bf16(a1, WF[(8 + nt) * 64 + lane], acc[nt], 0, 0, 0);
      }
      int r_hi = (lane >> 4) * 4;
#pragma unroll
      for (int nt = 0; nt < 8; ++nt) {
        int d = nt * 16 + (lane & 15);
        int h = d >> 6, dd = d & 63;
        int kc = dd >> 5, q = (dd >> 3) & 3, i = dd & 7;
#pragma unroll
        for (int j = 0; j < 4; ++j) {
          int m = w * 16 + r_hi + j;
          int mt = m >> 4, rr = m & 15;
          size_t idx = ((size_t)((yi * 2 + h) * 8 + mt * 2 + kc)) * 512 + (rr + (q << 4)) * 8 + i;
          pyf[idx] = f2bf(acc[nt][j]);
        }
      }
    } else {
      // -------------------- gallery+px: 64 rows of x -----------------------
      int rowbase = b * 64;
      const bf16x8* WPF = reinterpret_cast<const bf16x8*>(wpf);
      const bf16x8* WF = reinterpret_cast<const bf16x8*>(w1f);
      int rloc = rowbase + w * 16 + (lane & 15);
      const float* xb = x + (size_t)rloc * 512 + 8 * (lane >> 4);
      f32x4 acc1[4];
#pragma unroll
      for (int nt = 0; nt < 4; ++nt) acc1[nt] = (f32x4){0.f, 0.f, 0.f, 0.f};
#pragma unroll
      for (int q = 0; q < 4; ++q) {          // K quarters of 128
        if (q) __syncthreads();              // protect previous quarter's reads
#pragma unroll
        for (int it = 0; it < 32; ++it) {
          int idx = it * 256 + t;            // over 128*64
          int kq = idx >> 6, c = idx & 63;
          int l = (c & 15) + 16 * ((kq >> 3) & 3);
          int g = ((kq >> 5) & 3) * 4 + (c >> 4);
          wpf[g * 512 + l * 8 + (kq & 7)] = f2bf(Wp[(q * 128 + kq) * 64 + c]);
        }
        __syncthreads();
#pragma unroll
        for (int kk = 0; kk < 4; ++kk) {
          int kc = q * 4 + kk;
          bf16x8 a = load8_cvt(xb + 32 * kc);
#pragma unroll
          for (int nt = 0; nt < 4; ++nt)
            acc1[nt] = __builtin_amdgcn_mfma_f32_16x16x32_bf16(a, WPF[(kk * 4 + nt) * 64 + lane], acc1[nt], 0, 0, 0);
        }
      }
      // gelu -> own-wave gal tile (same-wave LDS RAW, no barrier needed)
#pragma unroll
      for (int nt = 0; nt < 4; ++nt)
#pragma unroll
        for (int j = 0; j < 4; ++j) {
          float s = acc1[nt][j];
          float ge = 0.5f * s * (1.0f + erff(s * 0.70710678118654752f));
          int rl = (lane >> 4) * 4 + j;
          int c = nt * 16 + (lane & 15);
          gal[w][rl * 72 + c] = f2bf(ge);
        }
      const unsigned short* gp = &gal[w][(lane & 15) * 72 + 8 * (lane >> 4)];
      bf16x8 g0 = *reinterpret_cast<const bf16x8*>(gp);
      bf16x8 g1 = *reinterpret_cast<const bf16x8*>(gp + 32);
      f32x4 acc2[8];
#pragma unroll
      for (int nt = 0; nt < 8; ++nt) acc2[nt] = (f32x4){0.f, 0.f, 0.f, 0.f};
#pragma unroll
      for (int nt = 0; nt < 8; ++nt) {
        acc2[nt] = __builtin_amdgcn_mfma_f32_16x16x32_bf16(g0, WF[nt * 64 + lane], acc2[nt], 0, 0, 0);
        acc2[nt] = __builtin_amdgcn_mfma_f32_16x16x32_bf16(g1, WF[(8 + nt) * 64 + lane], acc2[nt], 0, 0, 0);
      }
      int r_hi = (lane >> 4) * 4;
#pragma unroll
      for (int nt = 0; nt < 8; ++nt) {
        int d = nt * 16 + (lane & 15);
        int h = d >> 6, dd = d & 63;
        int kc = dd >> 5, q2 = (dd >> 3) & 3, i = dd & 7;
#pragma unroll
        for (int j = 0; j < 4; ++j) {
          int row = rowbase + w * 16 + r_hi + j;
          int xi = row / 48, n = row % 48;
          int nt3 = n >> 4, rr = n & 15;
          size_t idx = ((size_t)((xi * 2 + h) * 6 + nt3 * 2 + kc)) * 512 + (rr + (q2 << 4)) * 8 + i;
          pxf[idx] = f2bf(acc2[nt][j]);
        }
      }
    }
  }

  // ===================== release (producers) + wait (all) ==================
  __syncthreads();   // HIP barrier drains vmcnt(0) per wave -> stores in local L2
  if (b < (int)NPROD && t == 0) {
    // RELEASE at agent scope -> compiler emits L2 writeback before the add:
    // all this block's pyf/pxf stores become visible at the coherence point.
    __hip_atomic_fetch_add(&flags[0], 1u, __ATOMIC_RELEASE, __HIP_MEMORY_SCOPE_AGENT);
  }
  if (t == 0) {
    while (__hip_atomic_load(&flags[0], __ATOMIC_RELAXED, __HIP_MEMORY_SCOPE_AGENT) != NPROD)
      __builtin_amdgcn_s_sleep(8);           // ~512 cy backoff per poll
  }
  __syncthreads();   // non-poll threads park at s_barrier (no memory traffic)

  // ================================ att ====================================
  {
    int yb2 = b >> 4, xq = b & 15;
    int yi = yb2 * 4 + w;
    int xi0 = xq * 6;
    const bf16x8* PA = reinterpret_cast<const bf16x8*>(pyf);
    const bf16x8* PB = reinterpret_cast<const bf16x8*>(pxf);

    f32x4 zero4 = {0.f, 0.f, 0.f, 0.f};
    asm volatile("" : "+v"(zero4));

    bf16x8 a[16];
    size_t abase = (size_t)(yi * 2) * 512 + lane;
#pragma unroll
    for (int f = 0; f < 8; ++f) {
      a[f]     = PA[abase + f * 64];
      a[8 + f] = PA[abase + 512 + f * 64];
    }
    float res[6];
#pragma unroll
    for (int g = 0; g < 6; ++g) {
      int xi = xi0 + g;
      f32x4 szw = {0.f, 0.f, 0.f, 0.f};
      f32x4 srw = {0.f, 0.f, 0.f, 0.f};
#pragma unroll
      for (int h = 0; h < 2; ++h) {
        size_t bbase = (size_t)((xi * 2 + h) * 6) * 64 + lane;
        bf16x8 bb[6];
#pragma unroll
        for (int f = 0; f < 6; ++f) bb[f] = PB[bbase + f * 64];
        float c3 = 0.3f * (h ? w2h1 : w2h0);
        float c7 = 0.7f * (h ? w2h1 : w2h0);
#pragma unroll
        for (int nt = 0; nt < 3; ++nt)
#pragma unroll
          for (int mt = 0; mt < 4; ++mt) {
            f32x4 acc = __builtin_amdgcn_mfma_f32_16x16x32_bf16(a[h * 8 + mt * 2], bb[nt * 2], zero4, 0, 0, 0);
            acc = __builtin_amdgcn_mfma_f32_16x16x32_bf16(a[h * 8 + mt * 2 + 1], bb[nt * 2 + 1], acc, 0, 0, 0);
            f32x4 mx = {fmaxf(acc[0], 0.f), fmaxf(acc[1], 0.f), fmaxf(acc[2], 0.f), fmaxf(acc[3], 0.f)};
            szw += acc * c3;
            srw += mx * c7;
          }
      }
      f32x4 t4 = szw + srw;
      float tot = (t4[0] + t4[1]) + (t4[2] + t4[3]);
#pragma unroll
      for (int off = 32; off >= 1; off >>= 1) tot += __shfl_xor(tot, off, 64);
      res[g] = tot;
    }
    if (lane == 0) {
#pragma unroll
      for (int g = 0; g < 6; ++g)
        out[yi * 96 + xi0 + g] = res[g] / (512.0f * nItem[xi0 + g]);
    }
  }
}

// ---------------------------------------------------------------------------
extern "C" void kernel_launch(void* const* d_in, const int* in_sizes, int n_in,
                              void* d_out, int out_size, void* d_ws, size_t ws_size,
                              hipStream_t stream) {
  const float* x     = (const float*)d_in[0]; // [96,48,512]
  const float* y     = (const float*)d_in[1]; // [96,64,64]
  const float* nItem = (const float*)d_in[2]; // [96]
  const float* Wp    = (const float*)d_in[3]; // [512,64]
  const float* W1    = (const float*)d_in[4]; // [64,128]
  const float* W2    = (const float*)d_in[5]; // [2,1]
  float* out = (float*)d_out;                 // [96,96,1]

  unsigned short* pyf = (unsigned short*)d_ws;         // 786432 u16 (1.5MB)
  unsigned short* pxf = pyf + 786432;                  // 589824 u16 (1.125MB)
  unsigned int* flags = (unsigned int*)(pxf + 589824); // 2 u32

  hipMemsetAsync(flags, 0, 8, stream);                 // tiny graph node: counter := 0
  hipLaunchKernelGGL(k_fused, dim3(NBLK), dim3(256), 0, stream,
                     x, y, Wp, W1, nItem, W2, pyf, pxf, flags, out);
}

// Round 6
// 35.519 us; speedup vs baseline: 2.0388x; 1.6034x over previous
//
#include <hip/hip_runtime.h>
#include <hip/hip_bf16.h>

// ---------------------------------------------------------------------------
// scores[y,x] = sum_h W2[h] * ( sum_{m,n} leaky( py[y,h,m,:].px[x,h,n,:] /8 ) ) / (nItem[x]*64)
// Two kernels (measured cheaper than in-kernel device sync: r3=34.9 vs r5=57):
//   k_prep (168 blocks): 0..71 gallery+px (64 x-rows; Wp frag image in 16KB
//          LDS quarters), 72..167 py (one yi each). All MFMA, bf16/f32-acc.
//   k_att  (768 blocks = 24 yb x 32 xq): wave = 1 yi x 3 xi, both heads.
//          A-frags register-resident; B-frags software-pipelined (prefetch
//          next (g,h) step during current step's 24 MFMAs). 12 waves/CU.
// leaky(z)=0.3z+0.7relu(z); scales+W2 folded: res += acc*(0.3*W2h) + relu(acc)*(0.7*W2h).
// Fragment map (A and B of mfma_f32_16x16x32_bf16, same map):
//   lane l holds (rc=l&15, k=8*(l>>4)+i), i=0..7.  C/D: col=l&15, row=(l>>4)*4+j.
// py image: [y][h][mt(4)][kc(2)][lane(64)][i(8)]
// px image: [x][h][nt(3)][kc(2)][lane(64)][i(8)]
// ---------------------------------------------------------------------------

typedef short bf16x8 __attribute__((ext_vector_type(8)));
typedef float f32x4 __attribute__((ext_vector_type(4)));

__device__ __forceinline__ unsigned short f2bf(float v) {
  __hip_bfloat16 b = __float2bfloat16(v);
  return *reinterpret_cast<unsigned short*>(&b);
}

__device__ __forceinline__ bf16x8 load8_cvt(const float* __restrict__ p) {
  f32x4 v0 = *reinterpret_cast<const f32x4*>(p);
  f32x4 v1 = *reinterpret_cast<const f32x4*>(p + 4);
  bf16x8 r;
  r[0] = (short)f2bf(v0[0]); r[1] = (short)f2bf(v0[1]);
  r[2] = (short)f2bf(v0[2]); r[3] = (short)f2bf(v0[3]);
  r[4] = (short)f2bf(v1[0]); r[5] = (short)f2bf(v1[1]);
  r[6] = (short)f2bf(v1[2]); r[7] = (short)f2bf(v1[3]);
  return r;
}

// ---------------------------------------------------------------------------
// K1: fused prep. LDS: w1f 16KB | wpf-quarter 16KB | gal 4x(16x72) 9KB.
// ---------------------------------------------------------------------------
__global__ __launch_bounds__(256) void k_prep(const float* __restrict__ x,
                                              const float* __restrict__ y,
                                              const float* __restrict__ Wp,
                                              const float* __restrict__ W1,
                                              unsigned short* __restrict__ pyf,
                                              unsigned short* __restrict__ pxf) {
  __shared__ unsigned short w1f[8192];      // frag f=kc*8+nt: [f][lane][8]  16KB
  __shared__ unsigned short wpf[8192];      // quarter: g=kk*4+nt: [g][lane][8] 16KB
  __shared__ unsigned short gal[4][1152];   // per-wave 16 x 72 (padded)      9KB
  int t = threadIdx.x;
  int lane = t & 63, w = t >> 6;
  int b = blockIdx.x;

  // build W1 frag image (both producer types need it)
#pragma unroll
  for (int it = 0; it < 32; ++it) {
    int idx = it * 256 + t;                // over 64*128
    int k = idx >> 7, d = idx & 127;
    int l = (d & 15) + 16 * ((k >> 3) & 3);
    int f = (k >> 5) * 8 + (d >> 4);
    w1f[f * 512 + l * 8 + (k & 7)] = f2bf(W1[idx]);
  }
  if (b >= 72) {
    // ------------------------- py: yi = b - 72 ---------------------------
    __syncthreads();
    int yi = b - 72;
    const bf16x8* WF = reinterpret_cast<const bf16x8*>(w1f);
    int row0 = yi * 64 + w * 16 + (lane & 15);
    const float* yb = y + (size_t)row0 * 64 + 8 * (lane >> 4);
    bf16x8 a0 = load8_cvt(yb);
    bf16x8 a1 = load8_cvt(yb + 32);
    f32x4 acc[8];
#pragma unroll
    for (int nt = 0; nt < 8; ++nt) acc[nt] = (f32x4){0.f, 0.f, 0.f, 0.f};
#pragma unroll
    for (int nt = 0; nt < 8; ++nt) {
      acc[nt] = __builtin_amdgcn_mfma_f32_16x16x32_bf16(a0, WF[nt * 64 + lane], acc[nt], 0, 0, 0);
      acc[nt] = __builtin_amdgcn_mfma_f32_16x16x32_bf16(a1, WF[(8 + nt) * 64 + lane], acc[nt], 0, 0, 0);
    }
    int r_hi = (lane >> 4) * 4;
#pragma unroll
    for (int nt = 0; nt < 8; ++nt) {
      int d = nt * 16 + (lane & 15);
      int h = d >> 6, dd = d & 63;
      int kc = dd >> 5, q = (dd >> 3) & 3, i = dd & 7;
#pragma unroll
      for (int j = 0; j < 4; ++j) {
        int m = w * 16 + r_hi + j;
        int mt = m >> 4, rr = m & 15;
        size_t idx = ((size_t)((yi * 2 + h) * 8 + mt * 2 + kc)) * 512 + (rr + (q << 4)) * 8 + i;
        pyf[idx] = f2bf(acc[nt][j]);
      }
    }
  } else {
    // -------------------- gallery+px: 64 rows of x -----------------------
    int rowbase = b * 64;
    const bf16x8* WPF = reinterpret_cast<const bf16x8*>(wpf);
    const bf16x8* WF = reinterpret_cast<const bf16x8*>(w1f);
    int rloc = rowbase + w * 16 + (lane & 15);
    const float* xb = x + (size_t)rloc * 512 + 8 * (lane >> 4);
    f32x4 acc1[4];
#pragma unroll
    for (int nt = 0; nt < 4; ++nt) acc1[nt] = (f32x4){0.f, 0.f, 0.f, 0.f};
#pragma unroll
    for (int q = 0; q < 4; ++q) {          // K quarters of 128
      if (q) __syncthreads();              // protect previous quarter's reads
#pragma unroll
      for (int it = 0; it < 32; ++it) {
        int idx = it * 256 + t;            // over 128*64
        int kq = idx >> 6, c = idx & 63;
        int l = (c & 15) + 16 * ((kq >> 3) & 3);
        int g = ((kq >> 5) & 3) * 4 + (c >> 4);
        wpf[g * 512 + l * 8 + (kq & 7)] = f2bf(Wp[(q * 128 + kq) * 64 + c]);
      }
      __syncthreads();
#pragma unroll
      for (int kk = 0; kk < 4; ++kk) {
        int kc = q * 4 + kk;
        bf16x8 a = load8_cvt(xb + 32 * kc);
#pragma unroll
        for (int nt = 0; nt < 4; ++nt)
          acc1[nt] = __builtin_amdgcn_mfma_f32_16x16x32_bf16(a, WPF[(kk * 4 + nt) * 64 + lane], acc1[nt], 0, 0, 0);
      }
    }
    // gelu -> own-wave gal tile (same-wave LDS RAW, no barrier needed)
#pragma unroll
    for (int nt = 0; nt < 4; ++nt)
#pragma unroll
      for (int j = 0; j < 4; ++j) {
        float s = acc1[nt][j];
        float ge = 0.5f * s * (1.0f + erff(s * 0.70710678118654752f));
        int rl = (lane >> 4) * 4 + j;
        int c = nt * 16 + (lane & 15);
        gal[w][rl * 72 + c] = f2bf(ge);
      }
    const unsigned short* gp = &gal[w][(lane & 15) * 72 + 8 * (lane >> 4)];
    bf16x8 g0 = *reinterpret_cast<const bf16x8*>(gp);
    bf16x8 g1 = *reinterpret_cast<const bf16x8*>(gp + 32);
    f32x4 acc2[8];
#pragma unroll
    for (int nt = 0; nt < 8; ++nt) acc2[nt] = (f32x4){0.f, 0.f, 0.f, 0.f};
#pragma unroll
    for (int nt = 0; nt < 8; ++nt) {
      acc2[nt] = __builtin_amdgcn_mfma_f32_16x16x32_bf16(g0, WF[nt * 64 + lane], acc2[nt], 0, 0, 0);
      acc2[nt] = __builtin_amdgcn_mfma_f32_16x16x32_bf16(g1, WF[(8 + nt) * 64 + lane], acc2[nt], 0, 0, 0);
    }
    int r_hi = (lane >> 4) * 4;
#pragma unroll
    for (int nt = 0; nt < 8; ++nt) {
      int d = nt * 16 + (lane & 15);
      int h = d >> 6, dd = d & 63;
      int kc = dd >> 5, q2 = (dd >> 3) & 3, i = dd & 7;
#pragma unroll
      for (int j = 0; j < 4; ++j) {
        int row = rowbase + w * 16 + r_hi + j;
        int xi = row / 48, n = row % 48;
        int nt3 = n >> 4, rr = n & 15;
        size_t idx = ((size_t)((xi * 2 + h) * 6 + nt3 * 2 + kc)) * 512 + (rr + (q2 << 4)) * 8 + i;
        pxf[idx] = f2bf(acc2[nt][j]);
      }
    }
  }
}

// ---------------------------------------------------------------------------
// K2: pairwise, software-pipelined. 768 blocks = 24 yb x 32 xq; block = 4
// waves (4 yi, same xq -> B shared via L1); wave = 1 yi x 3 xi, both heads.
// Steps s = h*3+g: prefetch B[s+1] before the 24 MFMAs of step s.
// ---------------------------------------------------------------------------
__global__ __launch_bounds__(256) void k_att(const unsigned short* __restrict__ pyf_u,
                                             const unsigned short* __restrict__ pxf_u,
                                             const float* __restrict__ nItem,
                                             const float* __restrict__ W2,
                                             float* __restrict__ out) {
  int lane = threadIdx.x & 63;
  int w = threadIdx.x >> 6;
  int bid = blockIdx.x;
  int yb = bid >> 5, xq = bid & 31;
  int yi = yb * 4 + w;
  int xi0 = xq * 3;
  const bf16x8* PA = reinterpret_cast<const bf16x8*>(pyf_u);
  const bf16x8* PB = reinterpret_cast<const bf16x8*>(pxf_u);

  float w2h0 = W2[0], w2h1 = W2[1];
  float nI0 = nItem[xi0], nI1 = nItem[xi0 + 1], nI2 = nItem[xi0 + 2];

  f32x4 zero4 = {0.f, 0.f, 0.f, 0.f};
  asm volatile("" : "+v"(zero4));          // pin zero C-operand

  // A-frags for both heads, register-resident (64 VGPR)
  bf16x8 A8[16];                           // [h*8 + mt*2 + kc]
  size_t abase = (size_t)(yi * 2) * 512 + lane;
#pragma unroll
  for (int f = 0; f < 8; ++f) {
    A8[f]     = PA[abase + f * 64];
    A8[8 + f] = PA[abase + 512 + f * 64];
  }

  float c3h0 = 0.3f * w2h0, c7h0 = 0.7f * w2h0;
  float c3h1 = 0.3f * w2h1, c7h1 = 0.7f * w2h1;

  bf16x8 Bc[6], Bn[6];
  size_t bb0 = (size_t)((xi0 * 2 + 0) * 6) * 64 + lane;  // s=0: g=0,h=0
#pragma unroll
  for (int f = 0; f < 6; ++f) Bc[f] = PB[bb0 + f * 64];

  f32x4 res4[3];
#pragma unroll
  for (int g = 0; g < 3; ++g) res4[g] = (f32x4){0.f, 0.f, 0.f, 0.f};

#pragma unroll
  for (int s = 0; s < 6; ++s) {
    const int h = s / 3, g = s % 3;
    if (s < 5) {                            // prefetch next step's B-frags
      const int s2 = s + 1, h2 = s2 / 3, g2 = s2 % 3;
      size_t bb = (size_t)(((xi0 + g2) * 2 + h2) * 6) * 64 + lane;
#pragma unroll
      for (int f = 0; f < 6; ++f) Bn[f] = PB[bb + f * 64];
    }
    const float c3 = h ? c3h1 : c3h0;
    const float c7 = h ? c7h1 : c7h0;
#pragma unroll
    for (int nt = 0; nt < 3; ++nt)
#pragma unroll
      for (int mt = 0; mt < 4; ++mt) {
        f32x4 acc = __builtin_amdgcn_mfma_f32_16x16x32_bf16(A8[h * 8 + mt * 2], Bc[nt * 2], zero4, 0, 0, 0);
        acc = __builtin_amdgcn_mfma_f32_16x16x32_bf16(A8[h * 8 + mt * 2 + 1], Bc[nt * 2 + 1], acc, 0, 0, 0);
        f32x4 mx = {fmaxf(acc[0], 0.f), fmaxf(acc[1], 0.f), fmaxf(acc[2], 0.f), fmaxf(acc[3], 0.f)};
        res4[g] += acc * c3;
        res4[g] += mx * c7;
      }
#pragma unroll
    for (int f = 0; f < 6; ++f) Bc[f] = Bn[f];  // renamed away by full unroll
  }

  float tot0 = (res4[0][0] + res4[0][1]) + (res4[0][2] + res4[0][3]);
  float tot1 = (res4[1][0] + res4[1][1]) + (res4[1][2] + res4[1][3]);
  float tot2 = (res4[2][0] + res4[2][1]) + (res4[2][2] + res4[2][3]);
#pragma unroll
  for (int off = 32; off >= 1; off >>= 1) {
    tot0 += __shfl_xor(tot0, off, 64);
    tot1 += __shfl_xor(tot1, off, 64);
    tot2 += __shfl_xor(tot2, off, 64);
  }
  if (lane == 0) {
    out[yi * 96 + xi0 + 0] = tot0 / (512.0f * nI0);
    out[yi * 96 + xi0 + 1] = tot1 / (512.0f * nI1);
    out[yi * 96 + xi0 + 2] = tot2 / (512.0f * nI2);
  }
}

// ---------------------------------------------------------------------------
extern "C" void kernel_launch(void* const* d_in, const int* in_sizes, int n_in,
                              void* d_out, int out_size, void* d_ws, size_t ws_size,
                              hipStream_t stream) {
  const float* x     = (const float*)d_in[0]; // [96,48,512]
  const float* y     = (const float*)d_in[1]; // [96,64,64]
  const float* nItem = (const float*)d_in[2]; // [96]
  const float* Wp    = (const float*)d_in[3]; // [512,64]
  const float* W1    = (const float*)d_in[4]; // [64,128]
  const float* W2    = (const float*)d_in[5]; // [2,1]
  float* out = (float*)d_out;                 // [96,96,1]

  unsigned short* pyf = (unsigned short*)d_ws;   // 786432 u16 (1.5MB)
  unsigned short* pxf = pyf + 786432;            // 589824 u16 (1.125MB)

  hipLaunchKernelGGL(k_prep, dim3(168), dim3(256), 0, stream, x, y, Wp, W1, pyf, pxf);
  hipLaunchKernelGGL(k_att, dim3(768), dim3(256), 0, stream, pyf, pxf, nItem, W2, out);
}